// Round 9
// baseline (315.161 us; speedup 1.0000x reference)
//
#include <hip/hip_runtime.h>

// ---------------- problem constants ----------------
#define N_ANCH 221184      // H*W*A = 128*192*9
#define HW     24576       // H*W
#define Wd     192
#define AA     9
#define TOPN   6000
#define POSTN  300
#define CAND_CAP 8192
#define NWORDS 94          // ceil(6016/64) words of suppression bits
#define NCHUNK 47          // 6016 / 128

typedef unsigned long long u64;

// anchor widths/heights (== ws2/hs2 of the reference, exact small ints)
__device__ const float c_aw[9] = {184.f,368.f,736.f,128.f,256.f,512.f, 88.f,176.f,352.f};
__device__ const float c_ah[9] = { 96.f,192.f,384.f,128.f,256.f,512.f,176.f,352.f,704.f};

// shared box decode — used by decode_kernel AND rank_scatter so the FP
// sequence (and thus every bit of the box) is identical in both places.
__device__ __forceinline__ float4 decode_box(int a, int cell,
                                             const float* __restrict__ deltas,
                                             float info0, float info1, float info2,
                                             bool* valid) {
    int h = cell / Wd;
    int w = cell - h * Wd;
    const float* db = deltas + (size_t)(4 * a) * HW + cell;
    float dx = db[0];
    float dy = db[HW];
    float dw = db[2 * HW];
    float dh = db[3 * HW];
    dw = fminf(fmaxf(dw, -10.f), 10.f);
    dh = fminf(fmaxf(dh, -10.f), 10.f);

    float ww = c_aw[a], hh = c_ah[a];
    float cx = 16.f * (float)w + 8.f;   // exact
    float cy = 16.f * (float)h + 8.f;   // exact

    float pcx = __fadd_rn(__fmul_rn(dx, ww), cx);
    float pcy = __fadd_rn(__fmul_rn(dy, hh), cy);
    float pw  = __fmul_rn(expf(dw), ww);
    float ph  = __fmul_rn(expf(dh), hh);
    float hpw = __fmul_rn(0.5f, pw);
    float hph = __fmul_rn(0.5f, ph);
    float x1 = __fsub_rn(pcx, hpw);
    float x2 = __fadd_rn(pcx, hpw);
    float y1 = __fsub_rn(pcy, hph);
    float y2 = __fadd_rn(pcy, hph);

    float xmax = __fsub_rn(info1, 1.f);
    float ymax = __fsub_rn(info0, 1.f);
    x1 = fminf(fmaxf(x1, 0.f), xmax);
    x2 = fminf(fmaxf(x2, 0.f), xmax);
    y1 = fminf(fmaxf(y1, 0.f), ymax);
    y2 = fminf(fmaxf(y2, 0.f), ymax);

    float msz = __fmul_rn(16.f, info2);
    *valid = (__fadd_rn(__fsub_rn(x2, x1), 1.f) >= msz) &&
             (__fadd_rn(__fsub_rn(y2, y1), 1.f) >= msz);
    return make_float4(x1, y1, x2, y2);
}

// ------- init: zero hist256+state+cand (contiguous), vmask, hist64k -------
#define ZA_F4 4164    // (1024 + 64 + 65536) / 16
#define ZB_F4 48      // 768 / 16
#define ZC_F4 16384   // 262144 / 16  (hist64k, carved from mat base)
__global__ __launch_bounds__(256) void init_kernel(float4* zA, float4* zB,
                                                   float4* zC) {
    int t = blockIdx.x * 256 + threadIdx.x;
    float4 z = make_float4(0.f, 0.f, 0.f, 0.f);
    if (t < ZA_F4) zA[t] = z;
    else if (t < ZA_F4 + ZB_F4) zB[t - ZA_F4] = z;
    else if (t < ZA_F4 + ZB_F4 + ZC_F4) zC[t - ZA_F4 - ZB_F4] = z;
}

// thread t maps to (a = t/HW, cell = t%HW) so reads of scores/deltas are
// coalesced. Writes the 32-bit ordered key; builds BOTH the top-byte
// histogram (LDS-aggregated -> 256 global atomics/block) and the
// (first,second)-byte 64K-bucket histogram (one fire-and-forget global
// atomic per thread, ~3.4 hits/bucket -> no contention). The 64K hist is
// what lets midselect avoid any full-key pass on a single CU.
__global__ __launch_bounds__(256) void decode_kernel(const float* __restrict__ scores,
                                                     const float* __restrict__ deltas,
                                                     const float* __restrict__ iminfo,
                                                     unsigned int* __restrict__ keys,
                                                     unsigned int* __restrict__ hist256,
                                                     unsigned int* __restrict__ hist64k) {
    __shared__ unsigned int lh[256];
    lh[threadIdx.x] = 0u;
    __syncthreads();
    int t = blockIdx.x * 256 + threadIdx.x;
    int a = t / HW;
    int cell = t - a * HW;
    float score = scores[(AA + a) * HW + cell];
    bool valid;
    (void)decode_box(a, cell, deltas, iminfo[0], iminfo[1], iminfo[2], &valid);
    unsigned int sb = __float_as_uint(score);
    // flip to ordered-uint; invalid -> key of -inf (0x007FFFFF)
    unsigned int key = valid ? ((sb & 0x80000000u) ? ~sb : (sb | 0x80000000u))
                             : 0x007FFFFFu;
    keys[t] = key;
    atomicAdd(&hist64k[key >> 16], 1u);
    atomicAdd(&lh[key >> 24], 1u);
    __syncthreads();
    if (lh[threadIdx.x]) atomicAdd(&hist256[threadIdx.x], lh[threadIdx.x]);
}

// tiny threshold select: 1 block, 256 threads, ~1.3 KB of reads.
// (1) suffix-sum hist256 -> prefix byte P + within-bucket rank;
// (2) suffix-sum row P of hist64k -> 16-bit threshold T -> state[0].
// Replaces the old single-CU double-pass over 884 KB of keys.
__global__ __launch_bounds__(256) void midselect_kernel(const unsigned int* __restrict__ hist256,
                                                        const unsigned int* __restrict__ hist64k,
                                                        unsigned int* __restrict__ state) {
    __shared__ unsigned int sfx[256];
    __shared__ unsigned int sP, sRank;
    int t = threadIdx.x;
    sfx[t] = hist256[t];
    __syncthreads();
    for (int d = 1; d < 256; d <<= 1) {
        unsigned int v = (t + d < 256) ? sfx[t + d] : 0u;
        __syncthreads();
        sfx[t] += v;
        __syncthreads();
    }
    {
        unsigned int ge = sfx[t];
        unsigned int gt = (t < 255) ? sfx[t + 1] : 0u;
        if (ge >= TOPN && gt < TOPN) { sP = (unsigned int)t; sRank = TOPN - gt; }
    }
    __syncthreads();
    unsigned int P = sP, rank = sRank;
    sfx[t] = hist64k[(P << 8) + (unsigned int)t];
    __syncthreads();
    for (int d = 1; d < 256; d <<= 1) {
        unsigned int v = (t + d < 256) ? sfx[t + d] : 0u;
        __syncthreads();
        sfx[t] += v;
        __syncthreads();
    }
    {
        unsigned int ge = sfx[t];
        unsigned int gt = (t < 255) ? sfx[t + 1] : 0u;
        if (ge >= rank && gt < rank)
            state[0] = (P << 24) | ((unsigned int)t << 16);
    }
}

// take all keys >= T (boundary bucket fully included; cc ~6000+bucket < 8192)
__global__ __launch_bounds__(256) void compact_kernel(const unsigned int* __restrict__ keys,
                                                      unsigned int* __restrict__ state,
                                                      u64* __restrict__ cand) {
    int t = blockIdx.x * 256 + threadIdx.x;
    unsigned int k = keys[t];
    unsigned int T = state[0];
    if (k >= T) {
        unsigned int pos = atomicAdd(&state[2], 1u);
        if (pos < CAND_CAP) {
            int a = t / HW;
            int cell = t - a * HW;
            unsigned int aidx = (unsigned int)(cell * 9 + a);  // reference anchor index
            cand[pos] = ((u64)k << 32) | (u64)(~aidx);
        }
    }
}

// fused exact-rank + scatter. rank[i] = #{j : key_j > key_i}; keys distinct
// (index in low bits) -> rank == sorted position (score desc, index asc —
// lax.top_k order). 256 blocks, 8 threads per i (32 i's/block); j-loop is
// interleaved (jj = part + 8k) so each wave-instruction reads 8 CONSECUTIVE
// ulonglong2s (conflict-free, broadcast across the 8 i-groups).
__global__ __launch_bounds__(256) void rank_scatter_kernel(const u64* __restrict__ cand,
                                                           const float* __restrict__ deltas,
                                                           const float* __restrict__ iminfo,
                                                           float4* __restrict__ tb,
                                                           u64* __restrict__ vmask) {
    __shared__ u64 s[CAND_CAP];
    for (int j = threadIdx.x; j < CAND_CAP; j += 256) s[j] = cand[j];
    int part = threadIdx.x & 7;
    int i = blockIdx.x * 32 + (threadIdx.x >> 3);
    u64 k = cand[i];
    __syncthreads();
    const ulonglong2* sv = (const ulonglong2*)s;
    unsigned int cnt = 0;
    #pragma unroll 8
    for (int jj = part; jj < CAND_CAP / 2; jj += 8) {
        ulonglong2 v = sv[jj];
        cnt += (v.x > k) ? 1u : 0u;
        cnt += (v.y > k) ? 1u : 0u;
    }
    cnt += __shfl_xor(cnt, 1);
    cnt += __shfl_xor(cnt, 2);
    cnt += __shfl_xor(cnt, 4);
    if (part == 0 && k != 0ull && cnt < TOPN) {
        unsigned int aidx = ~((unsigned int)k);
        int a = (int)(aidx % 9u);
        int cell = (int)(aidx / 9u);
        bool valid;
        float4 box = decode_box(a, cell, deltas, iminfo[0], iminfo[1], iminfo[2], &valid);
        tb[cnt] = box;
        if ((unsigned int)(k >> 32) != 0x007FFFFFu)
            atomicOr(&vmask[cnt >> 6], 1ull << (cnt & 63));
    }
}

// suppression bit-matrix, upper-triangle word-blocks only.
__global__ __launch_bounds__(64) void nms_matrix_kernel(const float4* __restrict__ tb,
                                                        u64* __restrict__ mat) {
    if (blockIdx.x < blockIdx.y) return;
    __shared__ float4 cb[64];
    int t = threadIdx.x;
    int c0 = blockIdx.x * 64;
    int col = c0 + t;
    cb[t] = (col < TOPN) ? tb[col] : make_float4(0.f, 0.f, 0.f, 0.f);
    __syncthreads();
    int row = blockIdx.y * 64 + t;
    if (row >= TOPN) return;
    float4 rb = tb[row];
    float rA = (rb.z - rb.x) * (rb.w - rb.y);
    u64 mask = 0ull;
    for (int c = 0; c < 64; ++c) {
        if (c0 + c >= TOPN) break;
        float4 b = cb[c];
        float lx = fmaxf(rb.x, b.x), ly = fmaxf(rb.y, b.y);
        float rx = fminf(rb.z, b.z), ry = fminf(rb.w, b.w);
        float iw = fmaxf(rx - lx, 0.f), ih = fmaxf(ry - ly, 0.f);
        float inter = iw * ih;
        float bA = (b.z - b.x) * (b.w - b.y);
        float iou = inter / ((rA + bA) - inter);
        if (iou > 0.7f) mask |= (1ull << c);   // NaN compares false, as in numpy
    }
    mat[(size_t)row * NWORDS + blockIdx.x] = mask;
}

// 64-bit readlane with wave-uniform index (v_readlane — much cheaper than
// ds_bpermute-based __shfl).
__device__ __forceinline__ u64 rdl64(u64 v, int l) {
    unsigned int lo = (unsigned int)__builtin_amdgcn_readlane((int)(unsigned int)v, l);
    unsigned int hi = (unsigned int)__builtin_amdgcn_readlane((int)(unsigned int)(v >> 32), l);
    return ((u64)hi << 32) | (u64)lo;
}

// single-wave greedy scan, 128-box chunks (47 sequential steps). ROUND-0
// structure, verbatim — proven 66 µs / FETCH 114 KB / VGPR 36. Rounds 1-7
// established that every deeper pipeline (register or producer/consumer)
// loses to this on sync/spill/publish overhead.
//  - diagonal 128x128 bit-block prefetched ONE CHUNK AHEAD into registers
//  - in-chunk greedy: wave-uniform ALU + 4 readlanes per kept box
//  - propagation: lane w owns removal words w / 64+w; batched 8 kept deep
__global__ __launch_bounds__(64) void nms_scan_kernel(const u64* __restrict__ mat,
                                                      const u64* __restrict__ vmask,
                                                      const float4* __restrict__ tb,
                                                      float* __restrict__ out) {
    int lane = threadIdx.x;
    u64 r0 = ~vmask[lane];
    u64 r1 = (lane < NWORDS - 64) ? ~vmask[64 + lane] : ~0ull;
    __shared__ int kept[POSTN];
    int cnt = 0;

    u64 a0, a1, b0, b1;
    {
        ulonglong2 vA = *(const ulonglong2*)(mat + (size_t)lane * NWORDS);
        ulonglong2 vB = *(const ulonglong2*)(mat + (size_t)(64 + lane) * NWORDS);
        a0 = vA.x; a1 = vA.y; b0 = vB.x; b1 = vB.y;
    }
    for (int c = 0; c < NCHUNK; ++c) {
        u64 na0 = 0, na1 = 0, nb0 = 0, nb1 = 0;
        if (c + 1 < NCHUNK) {
            const u64* pA = mat + (size_t)((c + 1) * 128 + lane) * NWORDS + 2 * (c + 1);
            const u64* pB = mat + (size_t)((c + 1) * 128 + 64 + lane) * NWORDS + 2 * (c + 1);
            ulonglong2 vA = *(const ulonglong2*)pA;
            ulonglong2 vB = *(const ulonglong2*)pB;
            na0 = vA.x; na1 = vA.y; nb0 = vB.x; nb1 = vB.y;
        }
        int w2 = 2 * c;
        u64 s0 = (w2 < 64) ? rdl64(r0, w2) : rdl64(r1, w2 - 64);
        u64 s1 = (w2 + 1 < 64) ? rdl64(r0, w2 + 1) : rdl64(r1, w2 + 1 - 64);
        if ((s0 & s1) != ~0ull) {
            int base = c * 128;
            u64 rem0 = s0, rem1 = s1, k0 = 0ull, k1 = 0ull;
            while (cnt < POSTN) {
                int b;
                if (~rem0) b = __ffsll((u64)~rem0) - 1;
                else if (~rem1) b = 64 + __ffsll((u64)~rem1) - 1;
                else break;
                if (lane == 0) kept[cnt] = base + b;
                ++cnt;
                u64 w0, w1;
                if (b < 64) {
                    w0 = rdl64(a0, b); w1 = rdl64(a1, b);
                    k0 |= 1ull << b; rem0 |= 1ull << b;
                } else {
                    int bb = b - 64;
                    w0 = rdl64(b0, bb); w1 = rdl64(b1, bb);
                    k1 |= 1ull << bb; rem1 |= 1ull << bb;
                }
                rem0 |= w0; rem1 |= w1;
            }
            if (cnt >= POSTN) break;
            u64 f0 = 0ull, f1 = 0ull, m0 = k0, m1 = k1;
            while (m0 | m1) {
                int idxs[8];
                #pragma unroll
                for (int j = 0; j < 8; ++j) {
                    int b = -1;
                    if (m0) { b = __ffsll(m0) - 1; m0 &= m0 - 1; }
                    else if (m1) { b = 64 + __ffsll(m1) - 1; m1 &= m1 - 1; }
                    idxs[j] = b;
                }
                u64 v0[8], v1[8];
                #pragma unroll
                for (int j = 0; j < 8; ++j) {
                    v0[j] = 0ull; v1[j] = 0ull;
                    if (idxs[j] >= 0) {
                        const u64* row = mat + (size_t)(base + idxs[j]) * NWORDS;
                        v0[j] = row[lane];
                        if (lane < NWORDS - 64) v1[j] = row[64 + lane];
                    }
                }
                #pragma unroll
                for (int j = 0; j < 8; ++j) { f0 |= v0[j]; f1 |= v1[j]; }
            }
            r0 |= f0; r1 |= f1;
        }
        a0 = na0; a1 = na1; b0 = nb0; b1 = nb1;
    }

    for (int r = lane; r < POSTN; r += 64) {
        float4 b = make_float4(0.f, 0.f, 0.f, 0.f);
        if (r < cnt) b = tb[kept[r]];
        float* o = out + r * 5;
        o[0] = 0.f; o[1] = b.x; o[2] = b.y; o[3] = b.z; o[4] = b.w;
    }
}

// ---------------- host launcher ----------------
extern "C" void kernel_launch(void* const* d_in, const int* in_sizes, int n_in,
                              void* d_out, int out_size, void* d_ws, size_t ws_size,
                              hipStream_t stream) {
    const float* scores = (const float*)d_in[0];
    const float* deltas = (const float*)d_in[1];
    const float* iminfo = (const float*)d_in[2];
    float* out = (float*)d_out;

    char* ws = (char*)d_ws;
    // workspace layout (16B-aligned), total 5,572,416 bytes
    unsigned int* keys    = (unsigned int*)(ws + 0);          // 221184*4  = 884736
    unsigned int* hist256 = (unsigned int*)(ws + 884736);     // 256*4     = 1024
    unsigned int* state   = (unsigned int*)(ws + 885760);     // 64
    u64*          cand    = (u64*)(ws + 885824);              // 8192*8    = 65536
    float4*       tb      = (float4*)(ws + 951360);           // 6016*16   = 96256
    u64*          vmask   = (u64*)(ws + 1047616);             // 768
    u64*          mat     = (u64*)(ws + 1048384);             // 6016*94*8 = 4524032
    // hist64k reuses mat's first 256 KB: last read (midselect) precedes
    // nms_matrix's first write -> no extra workspace needed.
    unsigned int* hist64k = (unsigned int*)(ws + 1048384);    // 65536*4   = 262144

    const int NB = N_ANCH / 256;   // 864 exactly

    init_kernel<<<81, 256, 0, stream>>>((float4*)hist256, (float4*)vmask,
                                        (float4*)hist64k);
    decode_kernel<<<NB, 256, 0, stream>>>(scores, deltas, iminfo, keys,
                                          hist256, hist64k);
    midselect_kernel<<<1, 256, 0, stream>>>(hist256, hist64k, state);
    compact_kernel<<<NB, 256, 0, stream>>>(keys, state, cand);
    rank_scatter_kernel<<<CAND_CAP / 32, 256, 0, stream>>>(cand, deltas, iminfo, tb, vmask);
    nms_matrix_kernel<<<dim3(NWORDS, NWORDS), 64, 0, stream>>>(tb, mat);
    nms_scan_kernel<<<1, 64, 0, stream>>>(mat, vmask, tb, out);
}

// Round 10
// 241.102 us; speedup vs baseline: 1.3072x; 1.3072x over previous
//
#include <hip/hip_runtime.h>

// ---------------- problem constants ----------------
#define N_ANCH 221184      // H*W*A = 128*192*9
#define HW     24576       // H*W
#define Wd     192
#define AA     9
#define TOPN   6000
#define POSTN  300
#define CAND_CAP 8192
#define NWORDS 94          // ceil(6016/64) words of suppression bits
#define NCHUNK 47          // 6016 / 128

typedef unsigned long long u64;

// anchor widths/heights (== ws2/hs2 of the reference, exact small ints)
__device__ const float c_aw[9] = {184.f,368.f,736.f,128.f,256.f,512.f, 88.f,176.f,352.f};
__device__ const float c_ah[9] = { 96.f,192.f,384.f,128.f,256.f,512.f,176.f,352.f,704.f};

// shared box decode — used by decode_kernel AND rank_scatter so the FP
// sequence (and thus every bit of the box) is identical in both places.
__device__ __forceinline__ float4 decode_box(int a, int cell,
                                             const float* __restrict__ deltas,
                                             float info0, float info1, float info2,
                                             bool* valid) {
    int h = cell / Wd;
    int w = cell - h * Wd;
    const float* db = deltas + (size_t)(4 * a) * HW + cell;
    float dx = db[0];
    float dy = db[HW];
    float dw = db[2 * HW];
    float dh = db[3 * HW];
    dw = fminf(fmaxf(dw, -10.f), 10.f);
    dh = fminf(fmaxf(dh, -10.f), 10.f);

    float ww = c_aw[a], hh = c_ah[a];
    float cx = 16.f * (float)w + 8.f;   // exact
    float cy = 16.f * (float)h + 8.f;   // exact

    float pcx = __fadd_rn(__fmul_rn(dx, ww), cx);
    float pcy = __fadd_rn(__fmul_rn(dy, hh), cy);
    float pw  = __fmul_rn(expf(dw), ww);
    float ph  = __fmul_rn(expf(dh), hh);
    float hpw = __fmul_rn(0.5f, pw);
    float hph = __fmul_rn(0.5f, ph);
    float x1 = __fsub_rn(pcx, hpw);
    float x2 = __fadd_rn(pcx, hpw);
    float y1 = __fsub_rn(pcy, hph);
    float y2 = __fadd_rn(pcy, hph);

    float xmax = __fsub_rn(info1, 1.f);
    float ymax = __fsub_rn(info0, 1.f);
    x1 = fminf(fmaxf(x1, 0.f), xmax);
    x2 = fminf(fmaxf(x2, 0.f), xmax);
    y1 = fminf(fmaxf(y1, 0.f), ymax);
    y2 = fminf(fmaxf(y2, 0.f), ymax);

    float msz = __fmul_rn(16.f, info2);
    *valid = (__fadd_rn(__fsub_rn(x2, x1), 1.f) >= msz) &&
             (__fadd_rn(__fsub_rn(y2, y1), 1.f) >= msz);
    return make_float4(x1, y1, x2, y2);
}

// ------- init: zero hist256+state+cand (contiguous), vmask, h2 ------------
#define ZA_F4 4164    // (1024 + 64 + 65536) / 16
#define ZB_F4 48      // 768 / 16
#define ZC_F4 64      // 1024 / 16  (h2, carved from mat base)
__global__ __launch_bounds__(256) void init_kernel(float4* zA, float4* zB,
                                                   float4* zC) {
    int t = blockIdx.x * 256 + threadIdx.x;
    float4 z = make_float4(0.f, 0.f, 0.f, 0.f);
    if (t < ZA_F4) zA[t] = z;
    else if (t < ZA_F4 + ZB_F4) zB[t - ZA_F4] = z;
    else if (t < ZA_F4 + ZB_F4 + ZC_F4) zC[t - ZA_F4 - ZB_F4] = z;
}

// thread t maps to (a = t/HW, cell = t%HW) so reads of scores/deltas are
// coalesced. Writes the 32-bit ordered key; builds the top-BYTE histogram
// LDS-aggregated (256 global atomics per block). ROUND-8 form — round 9
// proved per-key device atomics on a 64K hist are a 94 µs contention bomb
// (float keys cluster into ~128 hot 16-bit buckets).
__global__ __launch_bounds__(256) void decode_kernel(const float* __restrict__ scores,
                                                     const float* __restrict__ deltas,
                                                     const float* __restrict__ iminfo,
                                                     unsigned int* __restrict__ keys,
                                                     unsigned int* __restrict__ hist256) {
    __shared__ unsigned int lh[256];
    lh[threadIdx.x] = 0u;
    __syncthreads();
    int t = blockIdx.x * 256 + threadIdx.x;
    int a = t / HW;
    int cell = t - a * HW;
    float score = scores[(AA + a) * HW + cell];
    bool valid;
    (void)decode_box(a, cell, deltas, iminfo[0], iminfo[1], iminfo[2], &valid);
    unsigned int sb = __float_as_uint(score);
    // flip to ordered-uint; invalid -> key of -inf (0x007FFFFF)
    unsigned int key = valid ? ((sb & 0x80000000u) ? ~sb : (sb | 0x80000000u))
                             : 0x007FFFFFu;
    keys[t] = key;
    atomicAdd(&lh[key >> 24], 1u);
    __syncthreads();
    if (lh[threadIdx.x]) atomicAdd(&hist256[threadIdx.x], lh[threadIdx.x]);
}

// per-block suffix-scan of hist256 -> prefix byte P (and rank if wanted).
// Pure function of hist256 — every block computes the same values.
__device__ __forceinline__ void scanP(const unsigned int* __restrict__ hist256,
                                      unsigned int* sfx, unsigned int* sP,
                                      unsigned int* sRank, int t) {
    sfx[t] = hist256[t];
    __syncthreads();
    for (int d = 1; d < 256; d <<= 1) {
        unsigned int v = (t + d < 256) ? sfx[t + d] : 0u;
        __syncthreads();
        sfx[t] += v;
        __syncthreads();
    }
    unsigned int ge = sfx[t];
    unsigned int gt = (t < 255) ? sfx[t + 1] : 0u;
    if (ge >= TOPN && gt < TOPN) { *sP = (unsigned int)t; *sRank = TOPN - gt; }
    __syncthreads();
}

// parallel second-level histogram: 864 blocks; each block recomputes P from
// hist256 (1 KB, L2-hot), filters its 256 keys for top byte == P (~860
// matches grid-wide), LDS-aggregates their second byte, dumps nonzero
// counters to global h2 (~860 total device atomics — no contention).
// Replaces round-8's single-CU full-key pass.
__global__ __launch_bounds__(256) void hist2_kernel(const unsigned int* __restrict__ keys,
                                                    const unsigned int* __restrict__ hist256,
                                                    unsigned int* __restrict__ h2) {
    __shared__ unsigned int sfx[256];
    __shared__ unsigned int lh[256];
    __shared__ unsigned int sP, sRank;
    int t = threadIdx.x;
    lh[t] = 0u;
    scanP(hist256, sfx, &sP, &sRank, t);
    unsigned int P = sP;
    unsigned int k = keys[blockIdx.x * 256 + t];
    if ((k >> 24) == P) atomicAdd(&lh[(k >> 16) & 0xFFu], 1u);
    __syncthreads();
    if (lh[t]) atomicAdd(&h2[t], lh[t]);
}

// compact: per-block recompute P/rank (hist256) and T (h2 suffix), then
// take all keys >= T (boundary bucket fully included; ~6000+3 < 8192).
__global__ __launch_bounds__(256) void compact_kernel(const unsigned int* __restrict__ keys,
                                                      const unsigned int* __restrict__ hist256,
                                                      const unsigned int* __restrict__ h2,
                                                      unsigned int* __restrict__ state,
                                                      u64* __restrict__ cand) {
    __shared__ unsigned int sfx[256];
    __shared__ unsigned int sP, sRank, sT;
    int t = threadIdx.x;
    scanP(hist256, sfx, &sP, &sRank, t);
    unsigned int P = sP, rank = sRank;
    __syncthreads();
    sfx[t] = h2[t];
    __syncthreads();
    for (int d = 1; d < 256; d <<= 1) {
        unsigned int v = (t + d < 256) ? sfx[t + d] : 0u;
        __syncthreads();
        sfx[t] += v;
        __syncthreads();
    }
    {
        unsigned int ge = sfx[t];
        unsigned int gt = (t < 255) ? sfx[t + 1] : 0u;
        if (ge >= rank && gt < rank) sT = (P << 24) | ((unsigned int)t << 16);
    }
    __syncthreads();
    unsigned int T = sT;
    int i = blockIdx.x * 256 + t;
    unsigned int k = keys[i];
    if (k >= T) {
        unsigned int pos = atomicAdd(&state[2], 1u);
        if (pos < CAND_CAP) {
            int a = i / HW;
            int cell = i - a * HW;
            unsigned int aidx = (unsigned int)(cell * 9 + a);  // reference anchor index
            cand[pos] = ((u64)k << 32) | (u64)(~aidx);
        }
    }
}

// fused exact-rank + scatter. rank[i] = #{j : key_j > key_i}; keys distinct
// (index in low bits) -> rank == sorted position (score desc, index asc —
// lax.top_k order). 256 blocks, 8 threads per i (32 i's/block); j-loop is
// interleaved (jj = part + 8k) so each wave-instruction reads 8 CONSECUTIVE
// ulonglong2s (conflict-free, broadcast across the 8 i-groups).
__global__ __launch_bounds__(256) void rank_scatter_kernel(const u64* __restrict__ cand,
                                                           const float* __restrict__ deltas,
                                                           const float* __restrict__ iminfo,
                                                           float4* __restrict__ tb,
                                                           u64* __restrict__ vmask) {
    __shared__ u64 s[CAND_CAP];
    for (int j = threadIdx.x; j < CAND_CAP; j += 256) s[j] = cand[j];
    int part = threadIdx.x & 7;
    int i = blockIdx.x * 32 + (threadIdx.x >> 3);
    u64 k = cand[i];
    __syncthreads();
    const ulonglong2* sv = (const ulonglong2*)s;
    unsigned int cnt = 0;
    #pragma unroll 8
    for (int jj = part; jj < CAND_CAP / 2; jj += 8) {
        ulonglong2 v = sv[jj];
        cnt += (v.x > k) ? 1u : 0u;
        cnt += (v.y > k) ? 1u : 0u;
    }
    cnt += __shfl_xor(cnt, 1);
    cnt += __shfl_xor(cnt, 2);
    cnt += __shfl_xor(cnt, 4);
    if (part == 0 && k != 0ull && cnt < TOPN) {
        unsigned int aidx = ~((unsigned int)k);
        int a = (int)(aidx % 9u);
        int cell = (int)(aidx / 9u);
        bool valid;
        float4 box = decode_box(a, cell, deltas, iminfo[0], iminfo[1], iminfo[2], &valid);
        tb[cnt] = box;
        if ((unsigned int)(k >> 32) != 0x007FFFFFu)
            atomicOr(&vmask[cnt >> 6], 1ull << (cnt & 63));
    }
}

// suppression bit-matrix, upper-triangle word-blocks only.
__global__ __launch_bounds__(64) void nms_matrix_kernel(const float4* __restrict__ tb,
                                                        u64* __restrict__ mat) {
    if (blockIdx.x < blockIdx.y) return;
    __shared__ float4 cb[64];
    int t = threadIdx.x;
    int c0 = blockIdx.x * 64;
    int col = c0 + t;
    cb[t] = (col < TOPN) ? tb[col] : make_float4(0.f, 0.f, 0.f, 0.f);
    __syncthreads();
    int row = blockIdx.y * 64 + t;
    if (row >= TOPN) return;
    float4 rb = tb[row];
    float rA = (rb.z - rb.x) * (rb.w - rb.y);
    u64 mask = 0ull;
    for (int c = 0; c < 64; ++c) {
        if (c0 + c >= TOPN) break;
        float4 b = cb[c];
        float lx = fmaxf(rb.x, b.x), ly = fmaxf(rb.y, b.y);
        float rx = fminf(rb.z, b.z), ry = fminf(rb.w, b.w);
        float iw = fmaxf(rx - lx, 0.f), ih = fmaxf(ry - ly, 0.f);
        float inter = iw * ih;
        float bA = (b.z - b.x) * (b.w - b.y);
        float iou = inter / ((rA + bA) - inter);
        if (iou > 0.7f) mask |= (1ull << c);   // NaN compares false, as in numpy
    }
    mat[(size_t)row * NWORDS + blockIdx.x] = mask;
}

// 64-bit readlane with wave-uniform index (v_readlane — much cheaper than
// ds_bpermute-based __shfl).
__device__ __forceinline__ u64 rdl64(u64 v, int l) {
    unsigned int lo = (unsigned int)__builtin_amdgcn_readlane((int)(unsigned int)v, l);
    unsigned int hi = (unsigned int)__builtin_amdgcn_readlane((int)(unsigned int)(v >> 32), l);
    return ((u64)hi << 32) | (u64)lo;
}

// single-wave greedy scan, 128-box chunks (47 sequential steps). ROUND-0
// structure, verbatim — proven 66 µs / FETCH 114 KB / VGPR 36. Rounds 1-7
// established that every deeper pipeline (register or producer/consumer)
// loses to this on sync/spill/publish overhead.
//  - diagonal 128x128 bit-block prefetched ONE CHUNK AHEAD into registers
//  - in-chunk greedy: wave-uniform ALU + 4 readlanes per kept box
//  - propagation: lane w owns removal words w / 64+w; batched 8 kept deep
__global__ __launch_bounds__(64) void nms_scan_kernel(const u64* __restrict__ mat,
                                                      const u64* __restrict__ vmask,
                                                      const float4* __restrict__ tb,
                                                      float* __restrict__ out) {
    int lane = threadIdx.x;
    u64 r0 = ~vmask[lane];
    u64 r1 = (lane < NWORDS - 64) ? ~vmask[64 + lane] : ~0ull;
    __shared__ int kept[POSTN];
    int cnt = 0;

    u64 a0, a1, b0, b1;
    {
        ulonglong2 vA = *(const ulonglong2*)(mat + (size_t)lane * NWORDS);
        ulonglong2 vB = *(const ulonglong2*)(mat + (size_t)(64 + lane) * NWORDS);
        a0 = vA.x; a1 = vA.y; b0 = vB.x; b1 = vB.y;
    }
    for (int c = 0; c < NCHUNK; ++c) {
        u64 na0 = 0, na1 = 0, nb0 = 0, nb1 = 0;
        if (c + 1 < NCHUNK) {
            const u64* pA = mat + (size_t)((c + 1) * 128 + lane) * NWORDS + 2 * (c + 1);
            const u64* pB = mat + (size_t)((c + 1) * 128 + 64 + lane) * NWORDS + 2 * (c + 1);
            ulonglong2 vA = *(const ulonglong2*)pA;
            ulonglong2 vB = *(const ulonglong2*)pB;
            na0 = vA.x; na1 = vA.y; nb0 = vB.x; nb1 = vB.y;
        }
        int w2 = 2 * c;
        u64 s0 = (w2 < 64) ? rdl64(r0, w2) : rdl64(r1, w2 - 64);
        u64 s1 = (w2 + 1 < 64) ? rdl64(r0, w2 + 1) : rdl64(r1, w2 + 1 - 64);
        if ((s0 & s1) != ~0ull) {
            int base = c * 128;
            u64 rem0 = s0, rem1 = s1, k0 = 0ull, k1 = 0ull;
            while (cnt < POSTN) {
                int b;
                if (~rem0) b = __ffsll((u64)~rem0) - 1;
                else if (~rem1) b = 64 + __ffsll((u64)~rem1) - 1;
                else break;
                if (lane == 0) kept[cnt] = base + b;
                ++cnt;
                u64 w0, w1;
                if (b < 64) {
                    w0 = rdl64(a0, b); w1 = rdl64(a1, b);
                    k0 |= 1ull << b; rem0 |= 1ull << b;
                } else {
                    int bb = b - 64;
                    w0 = rdl64(b0, bb); w1 = rdl64(b1, bb);
                    k1 |= 1ull << bb; rem1 |= 1ull << bb;
                }
                rem0 |= w0; rem1 |= w1;
            }
            if (cnt >= POSTN) break;
            u64 f0 = 0ull, f1 = 0ull, m0 = k0, m1 = k1;
            while (m0 | m1) {
                int idxs[8];
                #pragma unroll
                for (int j = 0; j < 8; ++j) {
                    int b = -1;
                    if (m0) { b = __ffsll(m0) - 1; m0 &= m0 - 1; }
                    else if (m1) { b = 64 + __ffsll(m1) - 1; m1 &= m1 - 1; }
                    idxs[j] = b;
                }
                u64 v0[8], v1[8];
                #pragma unroll
                for (int j = 0; j < 8; ++j) {
                    v0[j] = 0ull; v1[j] = 0ull;
                    if (idxs[j] >= 0) {
                        const u64* row = mat + (size_t)(base + idxs[j]) * NWORDS;
                        v0[j] = row[lane];
                        if (lane < NWORDS - 64) v1[j] = row[64 + lane];
                    }
                }
                #pragma unroll
                for (int j = 0; j < 8; ++j) { f0 |= v0[j]; f1 |= v1[j]; }
            }
            r0 |= f0; r1 |= f1;
        }
        a0 = na0; a1 = na1; b0 = nb0; b1 = nb1;
    }

    for (int r = lane; r < POSTN; r += 64) {
        float4 b = make_float4(0.f, 0.f, 0.f, 0.f);
        if (r < cnt) b = tb[kept[r]];
        float* o = out + r * 5;
        o[0] = 0.f; o[1] = b.x; o[2] = b.y; o[3] = b.z; o[4] = b.w;
    }
}

// ---------------- host launcher ----------------
extern "C" void kernel_launch(void* const* d_in, const int* in_sizes, int n_in,
                              void* d_out, int out_size, void* d_ws, size_t ws_size,
                              hipStream_t stream) {
    const float* scores = (const float*)d_in[0];
    const float* deltas = (const float*)d_in[1];
    const float* iminfo = (const float*)d_in[2];
    float* out = (float*)d_out;

    char* ws = (char*)d_ws;
    // workspace layout (16B-aligned), total 5,572,416 bytes
    unsigned int* keys    = (unsigned int*)(ws + 0);          // 221184*4  = 884736
    unsigned int* hist256 = (unsigned int*)(ws + 884736);     // 256*4     = 1024
    unsigned int* state   = (unsigned int*)(ws + 885760);     // 64
    u64*          cand    = (u64*)(ws + 885824);              // 8192*8    = 65536
    float4*       tb      = (float4*)(ws + 951360);           // 6016*16   = 96256
    u64*          vmask   = (u64*)(ws + 1047616);             // 768
    u64*          mat     = (u64*)(ws + 1048384);             // 6016*94*8 = 4524032
    // h2 reuses mat's first 1 KB: its last read (compact) precedes
    // nms_matrix's first write -> no extra workspace needed.
    unsigned int* h2      = (unsigned int*)(ws + 1048384);    // 256*4 = 1024

    const int NB = N_ANCH / 256;   // 864 exactly

    init_kernel<<<17, 256, 0, stream>>>((float4*)hist256, (float4*)vmask,
                                        (float4*)h2);
    decode_kernel<<<NB, 256, 0, stream>>>(scores, deltas, iminfo, keys, hist256);
    hist2_kernel<<<NB, 256, 0, stream>>>(keys, hist256, h2);
    compact_kernel<<<NB, 256, 0, stream>>>(keys, hist256, h2, state, cand);
    rank_scatter_kernel<<<CAND_CAP / 32, 256, 0, stream>>>(cand, deltas, iminfo, tb, vmask);
    nms_matrix_kernel<<<dim3(NWORDS, NWORDS), 64, 0, stream>>>(tb, mat);
    nms_scan_kernel<<<1, 64, 0, stream>>>(mat, vmask, tb, out);
}